// Round 10
// baseline (469.789 us; speedup 1.0000x reference)
//
#include <hip/hip_runtime.h>
#include <hip/hip_bf16.h>

#define VV 100000
#define EE 50
#define HH 64
#define BB 1024
#define TT 200
// 3H = 192

typedef float v4f __attribute__((ext_vector_type(4)));
typedef float f32x4 __attribute__((ext_vector_type(4)));
typedef short bf16x8 __attribute__((ext_vector_type(8)));

__device__ __forceinline__ float fsig(float x) {
    return 1.f / (1.f + __expf(-x));
}
__device__ __forceinline__ float ftanh(float x) {
    float e = __expf(2.f * x);
    return 1.f - 2.f / (e + 1.f);
}
// fp32 -> bf16 round-to-nearest-even (values are tame: no NaN/Inf handling needed)
__device__ __forceinline__ short f2bf(float f) {
    union { float f; unsigned u; } v; v.f = f;
    unsigned r = v.u + 0x7FFFu + ((v.u >> 16) & 1u);
    return (short)(r >> 16);
}

// ---------------- Kernel A: embW[v][c] = emb[v][:] @ Wx[:,c] + bi[c]  (both dirs via blockIdx.y) ----------------
__global__ __launch_bounds__(256) void embw_kernel(
    const float* __restrict__ emb,
    const float* __restrict__ Wx_f, const float* __restrict__ bi_f,
    const float* __restrict__ Wx_b, const float* __restrict__ bi_b,
    float* __restrict__ embW_f, float* __restrict__ embW_b)
{
    const float* Wx = blockIdx.y ? Wx_b : Wx_f;
    const float* bi = blockIdx.y ? bi_b : bi_f;
    float* embW     = blockIdx.y ? embW_b : embW_f;
    __shared__ float wx_lds[EE * 192];
    __shared__ float emb_lds[32 * EE];
    const int tid = threadIdx.x;
    const int v0 = blockIdx.x * 32;
    for (int i = tid; i < EE * 192; i += 256) wx_lds[i] = Wx[i];
    for (int i = tid; i < 32 * EE; i += 256) emb_lds[i] = emb[(size_t)v0 * EE + i];
    __syncthreads();
    const int cg = tid & 63;
    const int rg = tid >> 6;
    float acc[8][3];
    #pragma unroll
    for (int i = 0; i < 8; i++) {
        acc[i][0] = bi[cg];
        acc[i][1] = bi[cg + 64];
        acc[i][2] = bi[cg + 128];
    }
    for (int k = 0; k < EE; k++) {
        const float wx0 = wx_lds[k * 192 + cg];
        const float wx1 = wx_lds[k * 192 + cg + 64];
        const float wx2 = wx_lds[k * 192 + cg + 128];
        #pragma unroll
        for (int i = 0; i < 8; i++) {
            const float ev = emb_lds[(rg * 8 + i) * EE + k];
            acc[i][0] = fmaf(ev, wx0, acc[i][0]);
            acc[i][1] = fmaf(ev, wx1, acc[i][1]);
            acc[i][2] = fmaf(ev, wx2, acc[i][2]);
        }
    }
    #pragma unroll
    for (int i = 0; i < 8; i++) {
        const size_t row = (size_t)(v0 + rg * 8 + i) * 192;
        embW[row + cg]       = acc[i][0];
        embW[row + cg + 64]  = acc[i][1];
        embW[row + cg + 128] = acc[i][2];
    }
}

// ---------------- Kernel B v7: 4-wave k-split GRU; 48 weight regs/lane (spill-proof) ----------------
// Block = 256 thr per (b, dir). Lane: c = 16*w + (lane&15) -> hidden column (all 3 gates);
// kg = lane>>4 -> k-slice [16kg, 16kg+16). Partial dots combined via shfl_xor(16,32);
// gates computed redundantly in all kg lanes; h double-buffered in LDS -> 1 barrier/step.
__global__ __launch_bounds__(256, 2) void gru7_kernel(
    const int* __restrict__ ids,
    const float* __restrict__ embW_f, const float* __restrict__ embW_b,
    const float* __restrict__ Wh_f, const float* __restrict__ br_f,
    const float* __restrict__ Wh_b, const float* __restrict__ br_b,
    float* __restrict__ outb,     // [B, T, 128]
    float* __restrict__ hf_out)   // [B, 64]
{
    const int tid  = threadIdx.x;
    const int w    = tid >> 6;
    const int lane = tid & 63;
    const int l15  = lane & 15;
    const int kg   = lane >> 4;
    const int b    = blockIdx.x;
    const int dir  = blockIdx.y;
    const float* eW = dir ? embW_b : embW_f;
    const float* Wh = dir ? Wh_b : Wh_f;
    const float* br = dir ? br_b : br_f;
    const int c  = 16 * w + l15;
    const int k0 = 16 * kg;

    // 48 weights/lane: 3 gates x k-slice of 16
    v4f wz[4], wr[4], wn[4];
    #pragma unroll
    for (int q = 0; q < 4; q++) {
        #pragma unroll
        for (int e = 0; e < 4; e++) {
            const int k = k0 + 4 * q + e;
            wz[q][e] = Wh[k * 192 + c];
            wr[q][e] = Wh[k * 192 + 64 + c];
            wn[q][e] = Wh[k * 192 + 128 + c];
        }
    }
    const float brz = br[c], brr = br[64 + c], brn = br[128 + c];

    __shared__ __align__(16) float h_lds[2][64];
    __shared__ int ids_lds[TT];
    for (int i = tid; i < TT; i += 256) ids_lds[i] = ids[(size_t)b * TT + i];
    if (tid < 64) { h_lds[0][tid] = 0.f; h_lds[1][tid] = 0.f; }
    float hj = 0.f;   // this lane's h for column c (identical across kg lanes)
    __syncthreads();

    const int t0 = dir ? (TT - 1) : 0;
    const int dt = dir ? -1 : 1;

    int   id0 = ids_lds[t0];
    float gz0 = eW[(size_t)id0 * 192 + c];
    float gr0 = eW[(size_t)id0 * 192 + 64 + c];
    float gn0 = eW[(size_t)id0 * 192 + 128 + c];
    int   id1 = ids_lds[t0 + dt];
    float gz1 = eW[(size_t)id1 * 192 + c];
    float gr1 = eW[(size_t)id1 * 192 + 64 + c];
    float gn1 = eW[(size_t)id1 * 192 + 128 + c];

    float* obase = outb + (size_t)b * TT * 128 + dir * 64 + c;
    int cur = 0;

    for (int s = 0; s < TT; s++) {
        const int t = t0 + s * dt;
        // prefetch step s+2
        int id2 = 0; float gz2 = 0.f, gr2 = 0.f, gn2 = 0.f;
        if (s + 2 < TT) {
            id2 = ids_lds[t + 2 * dt];
            gz2 = eW[(size_t)id2 * 192 + c];
            gr2 = eW[(size_t)id2 * 192 + 64 + c];
            gn2 = eW[(size_t)id2 * 192 + 128 + c];
        }
        // partial dots over this lane's k-slice (h broadcast from LDS, conflict-free)
        const v4f* h4 = (const v4f*)&h_lds[cur][0];
        v4f aZ = {0.f, 0.f, 0.f, 0.f};
        v4f aR = {0.f, 0.f, 0.f, 0.f};
        v4f aN = {0.f, 0.f, 0.f, 0.f};
        #pragma unroll
        for (int q = 0; q < 4; q++) {
            const v4f hv = h4[4 * kg + q];
            aZ = __builtin_elementwise_fma(hv, wz[q], aZ);
            aR = __builtin_elementwise_fma(hv, wr[q], aR);
            aN = __builtin_elementwise_fma(hv, wn[q], aN);
        }
        float az = (aZ[0] + aZ[1]) + (aZ[2] + aZ[3]);
        float ar = (aR[0] + aR[1]) + (aR[2] + aR[3]);
        float an = (aN[0] + aN[1]) + (aN[2] + aN[3]);
        // combine the 4 k-groups: butterfly over lanes kg (offsets 16, 32)
        az += __shfl_xor(az, 16); az += __shfl_xor(az, 32);
        ar += __shfl_xor(ar, 16); ar += __shfl_xor(ar, 32);
        an += __shfl_xor(an, 16); an += __shfl_xor(an, 32);
        // gates (redundant across kg lanes; inputs identical)
        const float z  = fsig(gz0 + az + brz);
        const float r  = fsig(gr0 + ar + brr);
        const float hh = ftanh(gn0 + r * (an + brn));
        float hnew = z * hj + (1.f - z) * hh;
        hnew = (id0 != 0) ? hnew : hj;
        hj = hnew;
        if (kg == 0) {
            h_lds[cur ^ 1][c] = hj;          // write next buffer
            obase[(size_t)t * 128] = hj;
        }
        cur ^= 1;
        __syncthreads();                      // new h visible; old buffer free for overwrite
        id0 = id1; gz0 = gz1; gr0 = gr1; gn0 = gn1;
        id1 = id2; gz1 = gz2; gr1 = gr2; gn1 = gn2;
    }
    if (dir == 0 && kg == 0) hf_out[(size_t)b * 64 + c] = hj;
}

// ---------------- Kernel C v7: MFMA keys GEMM ----------------
// One block per b, 256 thr = 4 waves. keys[t, c] = out[b,t,:128] @ Wk[:, c].
// mfma_f32_16x16x32_bf16: A row = lane&15 (=t within tile), k = 8*(lane>>4)+j;
// B col = lane&15 (=c within n-tile), same k map; C/D col=lane&15, row=4*(lane>>4)+reg (m89-verified).
// Wk staged once into LDS, pre-swizzled to B-fragment order -> one ds_read_b128 per MFMA.
#define NTILE 13   // ceil(200/16)

__global__ __launch_bounds__(256) void attn7_kernel(
    const int* __restrict__ ids,
    const float* __restrict__ outb,   // [B,T,128] fp32
    const float* __restrict__ hf,     // [B,64]
    const float* __restrict__ Wk, const float* __restrict__ bk,
    const float* __restrict__ Wq, const float* __restrict__ bq,
    const float* __restrict__ We, const float* __restrict__ be,
    float* __restrict__ ctx)          // [B,128]
{
    __shared__ __align__(16) short wk_sw[1024 * 8];  // [slot][j]; slot = ks*256 + lhi*64 + nt*16 + l15
    __shared__ float q_lds[64];
    __shared__ float we_lds[64];
    __shared__ float e_lds[TT];
    __shared__ float part[4][128];
    const int b = blockIdx.x;
    const int tid = threadIdx.x;
    const int w = tid >> 6;
    const int lane = tid & 63;
    const int l15 = lane & 15;
    const int lhi = lane >> 4;

    // Stage Wk (fp32 -> bf16) into fragment-ordered LDS. Each thread fills 4 slots of 8 values.
    #pragma unroll
    for (int i = 0; i < 4; i++) {
        const int slot = tid + 256 * i;
        const int s_l15 = slot & 15;
        const int s_nt  = (slot >> 4) & 3;
        const int s_lhi = (slot >> 6) & 3;
        const int s_ks  = slot >> 8;
        const int kbase = 32 * s_ks + 8 * s_lhi;
        const int col   = 16 * s_nt + s_l15;
        bf16x8 v;
        #pragma unroll
        for (int jj = 0; jj < 8; jj++) v[jj] = f2bf(Wk[(size_t)(kbase + jj) * 64 + col]);
        *(bf16x8*)&wk_sw[slot * 8] = v;
    }
    // q[c] = bq[c] + hf[b] @ Wq[:,c] (wave 0; coalesced column reads)
    if (tid < 64) {
        float qc = bq[tid];
        const float* hfb = hf + (size_t)b * 64;
        for (int k = 0; k < 64; k++) qc = fmaf(hfb[k], Wq[k * 64 + tid], qc);
        q_lds[tid] = qc;
        we_lds[tid] = We[tid];
    }
    __syncthreads();

    // keys + energy, 16-row tiles round-robined over the 4 waves
    for (int tile = w; tile < NTILE; tile += 4) {
        const int t0 = tile * 16;
        const int t = t0 + l15;
        f32x4 acc[4];
        #pragma unroll
        for (int nt = 0; nt < 4; nt++) { acc[nt][0] = 0.f; acc[nt][1] = 0.f; acc[nt][2] = 0.f; acc[nt][3] = 0.f; }
        #pragma unroll
        for (int ks = 0; ks < 4; ks++) {
            bf16x8 a;
            if (t < TT) {
                const float* p = outb + ((size_t)b * TT + t) * 128 + 32 * ks + 8 * lhi;
                const float4 lo = *(const float4*)p;
                const float4 hi = *(const float4*)(p + 4);
                a[0] = f2bf(lo.x); a[1] = f2bf(lo.y); a[2] = f2bf(lo.z); a[3] = f2bf(lo.w);
                a[4] = f2bf(hi.x); a[5] = f2bf(hi.y); a[6] = f2bf(hi.z); a[7] = f2bf(hi.w);
            } else {
                #pragma unroll
                for (int jj = 0; jj < 8; jj++) a[jj] = 0;
            }
            #pragma unroll
            for (int nt = 0; nt < 4; nt++) {
                const bf16x8 bf = *(const bf16x8*)&wk_sw[(ks * 256 + lhi * 64 + nt * 16 + l15) * 8];
                acc[nt] = __builtin_amdgcn_mfma_f32_16x16x32_bf16(a, bf, acc[nt], 0, 0, 0);
            }
        }
        // energy partials: ep[r] = sum_c We[c] * tanh(keys[t0+4*lhi+r][c] + q[c]); c spread over l15 x nt
        float ep0 = 0.f, ep1 = 0.f, ep2 = 0.f, ep3 = 0.f;
        #pragma unroll
        for (int nt = 0; nt < 4; nt++) {
            const int c = 16 * nt + l15;
            const float qn = q_lds[c];
            const float wen = we_lds[c];
            ep0 = fmaf(wen, ftanh(acc[nt][0] + qn), ep0);
            ep1 = fmaf(wen, ftanh(acc[nt][1] + qn), ep1);
            ep2 = fmaf(wen, ftanh(acc[nt][2] + qn), ep2);
            ep3 = fmaf(wen, ftanh(acc[nt][3] + qn), ep3);
        }
        #pragma unroll
        for (int off = 1; off < 16; off <<= 1) {
            ep0 += __shfl_xor(ep0, off);
            ep1 += __shfl_xor(ep1, off);
            ep2 += __shfl_xor(ep2, off);
            ep3 += __shfl_xor(ep3, off);
        }
        if (l15 == 0) {
            const int rbase = t0 + 4 * lhi;
            if (rbase + 0 < TT) e_lds[rbase + 0] = ep0;
            if (rbase + 1 < TT) e_lds[rbase + 1] = ep1;
            if (rbase + 2 < TT) e_lds[rbase + 2] = ep2;
            if (rbase + 3 < TT) e_lds[rbase + 3] = ep3;
        }
    }
    __syncthreads();
    // softmax over t (wave 0)
    if (w == 0) {
        const float bev = be[0];
        for (int t = lane; t < TT; t += 64) {
            float e = e_lds[t] + bev;
            if (ids[(size_t)b * TT + t] == 0) e -= 1e9f;
            e_lds[t] = e;
        }
        float m = -1e30f;
        for (int t = lane; t < TT; t += 64) m = fmaxf(m, e_lds[t]);
        #pragma unroll
        for (int off = 32; off > 0; off >>= 1) m = fmaxf(m, __shfl_xor(m, off));
        float ssum = 0.f;
        for (int t = lane; t < TT; t += 64) { const float v = __expf(e_lds[t] - m); e_lds[t] = v; ssum += v; }
        #pragma unroll
        for (int off = 32; off > 0; off >>= 1) ssum += __shfl_xor(ssum, off);
        const float inv = 1.f / ssum;
        for (int t = lane; t < TT; t += 64) e_lds[t] *= inv;
    }
    __syncthreads();
    // context (fp32): wave w covers t ≡ w (mod 4)
    float c0 = 0.f, c1 = 0.f;
    for (int t = w; t < TT; t += 4) {
        const float* orow = outb + ((size_t)b * TT + t) * 128;
        const float wt = e_lds[t];
        c0 = fmaf(wt, orow[lane], c0);
        c1 = fmaf(wt, orow[64 + lane], c1);
    }
    part[w][lane] = c0;
    part[w][64 + lane] = c1;
    __syncthreads();
    if (tid < 128)
        ctx[(size_t)b * 128 + tid] = part[0][tid] + part[1][tid] + part[2][tid] + part[3][tid];
}

// ---------------- (fallback) GRU 3-wave kernel, recompute-gx variant ----------------
template<bool USE_EMBW>
__global__ __launch_bounds__(192, 2) void gru_kernel(
    const int* __restrict__ ids,
    const float* __restrict__ embW_f, const float* __restrict__ embW_b,
    const float* __restrict__ emb,
    const float* __restrict__ Wx_f, const float* __restrict__ bi_f,
    const float* __restrict__ Wx_b, const float* __restrict__ bi_b,
    const float* __restrict__ Wh_f, const float* __restrict__ br_f,
    const float* __restrict__ Wh_b, const float* __restrict__ br_b,
    float* __restrict__ outb, float* __restrict__ hf_out)
{
    constexpr int R = 4;
    __shared__ float h_lds[R][64];
    __shared__ float rg_lds[R][64];
    __shared__ float hh_lds[R][64];
    __shared__ int ids_lds[R * TT];
    const int tid = threadIdx.x;
    const int w = tid >> 6;
    const int j = tid & 63;
    const int dir = blockIdx.y;
    const int b0 = blockIdx.x * R;
    const float* embW = dir ? embW_b : embW_f;
    const float* Wh   = dir ? Wh_b : Wh_f;
    const float* br   = dir ? br_b : br_f;
    const float* Wx   = dir ? Wx_b : Wx_f;
    const float* bi   = dir ? bi_b : bi_f;
    const int c = w * 64 + j;

    float whc[64];
    #pragma unroll
    for (int k = 0; k < 64; k++) whc[k] = Wh[k * 192 + c];
    const float brc = br[c];
    float wxc[EE];
    float bic = 0.f;
    if (!USE_EMBW) {
        #pragma unroll
        for (int k = 0; k < EE; k++) wxc[k] = Wx[k * 192 + c];
        bic = bi[c];
    }
    for (int i = tid; i < R * TT; i += 192) ids_lds[i] = ids[(size_t)b0 * TT + i];
    if (w == 0) {
        #pragma unroll
        for (int r = 0; r < R; r++) h_lds[r][j] = 0.f;
    }
    __syncthreads();

    for (int s = 0; s < TT; s++) {
        const int t = dir ? (TT - 1 - s) : s;
        int idv[R];
        float gxv[R], accv[R];
        #pragma unroll
        for (int r = 0; r < R; r++) idv[r] = ids_lds[r * TT + t];
        if (USE_EMBW) {
            #pragma unroll
            for (int r = 0; r < R; r++) gxv[r] = embW[(size_t)idv[r] * 192 + c];
        } else {
            #pragma unroll
            for (int r = 0; r < R; r++) {
                float acc = bic;
                const float* er = emb + (size_t)idv[r] * EE;
                #pragma unroll
                for (int k = 0; k < EE; k++) acc = fmaf(er[k], wxc[k], acc);
                gxv[r] = acc;
            }
        }
        #pragma unroll
        for (int r = 0; r < R; r++) {
            float acc = brc;
            const float4* h4 = (const float4*)(&h_lds[r][0]);
            #pragma unroll
            for (int k4 = 0; k4 < 16; k4++) {
                const float4 hv = h4[k4];
                acc = fmaf(hv.x, whc[4 * k4 + 0], acc);
                acc = fmaf(hv.y, whc[4 * k4 + 1], acc);
                acc = fmaf(hv.z, whc[4 * k4 + 2], acc);
                acc = fmaf(hv.w, whc[4 * k4 + 3], acc);
            }
            accv[r] = acc;
        }
        float zg[R] = {};
        if (w == 1) {
            #pragma unroll
            for (int r = 0; r < R; r++) rg_lds[r][j] = fsig(gxv[r] + accv[r]);
        } else if (w == 0) {
            #pragma unroll
            for (int r = 0; r < R; r++) zg[r] = fsig(gxv[r] + accv[r]);
        }
        __syncthreads();
        if (w == 2) {
            #pragma unroll
            for (int r = 0; r < R; r++)
                hh_lds[r][j] = ftanh(gxv[r] + rg_lds[r][j] * accv[r]);
        }
        __syncthreads();
        if (w == 0) {
            #pragma unroll
            for (int r = 0; r < R; r++) {
                const float hold = h_lds[r][j];
                float hnew = hold;
                if (idv[r] != 0) {
                    const float hh = hh_lds[r][j];
                    hnew = zg[r] * hold + (1.f - zg[r]) * hh;
                }
                h_lds[r][j] = hnew;
                outb[((size_t)(b0 + r) * TT + t) * 128 + dir * 64 + j] = hnew;
            }
        }
        __syncthreads();
    }
    if (dir == 0 && w == 0) {
        #pragma unroll
        for (int r = 0; r < R; r++) hf_out[(size_t)(b0 + r) * 64 + j] = h_lds[r][j];
    }
}

extern "C" void kernel_launch(void* const* d_in, const int* in_sizes, int n_in,
                              void* d_out, int out_size, void* d_ws, size_t ws_size,
                              hipStream_t stream) {
    const int*   ids  = (const int*)d_in[0];
    const float* emb  = (const float*)d_in[1];
    const float* Wx_f = (const float*)d_in[2];
    const float* Wh_f = (const float*)d_in[3];
    const float* bi_f = (const float*)d_in[4];
    const float* br_f = (const float*)d_in[5];
    const float* Wx_b = (const float*)d_in[6];
    const float* Wh_b = (const float*)d_in[7];
    const float* bi_b = (const float*)d_in[8];
    const float* br_b = (const float*)d_in[9];
    const float* Wk   = (const float*)d_in[10];
    const float* bk   = (const float*)d_in[11];
    const float* Wq   = (const float*)d_in[12];
    const float* bq   = (const float*)d_in[13];
    const float* We   = (const float*)d_in[14];
    const float* be   = (const float*)d_in[15];
    float* ctx = (float*)d_out;

    float* ws = (float*)d_ws;
    const size_t embw_elems = (size_t)VV * 192;
    const size_t out_elems  = (size_t)BB * TT * 128;
    const size_t hf_elems   = (size_t)BB * 64;
    const size_t need_embw  = (2 * embw_elems + out_elems + hf_elems) * sizeof(float);
    const bool use_embw = (ws_size >= need_embw);

    float *embW_f = nullptr, *embW_b = nullptr, *outb, *hf;
    if (use_embw) {
        embW_f = ws;
        embW_b = embW_f + embw_elems;
        outb   = embW_b + embw_elems;
        hf     = outb + out_elems;
    } else {
        outb = ws;
        hf   = outb + out_elems;
    }

    if (use_embw) {
        embw_kernel<<<dim3(VV / 32, 2), 256, 0, stream>>>(
            emb, Wx_f, bi_f, Wx_b, bi_b, embW_f, embW_b);
        gru7_kernel<<<dim3(BB, 2), 256, 0, stream>>>(
            ids, embW_f, embW_b, Wh_f, br_f, Wh_b, br_b, outb, hf);
    } else {
        gru_kernel<false><<<dim3(BB / 4, 2), 192, 0, stream>>>(
            ids, embW_f, embW_b, emb, Wx_f, bi_f, Wx_b, bi_b,
            Wh_f, br_f, Wh_b, br_b, outb, hf);
    }
    attn7_kernel<<<BB, 256, 0, stream>>>(ids, outb, hf, Wk, bk, Wq, bq, We, be, ctx);
}

// Round 11
// 327.171 us; speedup vs baseline: 1.4359x; 1.4359x over previous
//
#include <hip/hip_runtime.h>
#include <hip/hip_bf16.h>

#define VV 100000
#define EE 50
#define HH 64
#define BB 1024
#define TT 200
// 3H = 192

typedef float v4f __attribute__((ext_vector_type(4)));
typedef float f32x4 __attribute__((ext_vector_type(4)));
typedef short bf16x8 __attribute__((ext_vector_type(8)));
typedef _Float16 f16x8 __attribute__((ext_vector_type(8)));

__device__ __forceinline__ float fsig(float x) {
    return 1.f / (1.f + __expf(-x));
}
__device__ __forceinline__ float ftanh(float x) {
    float e = __expf(2.f * x);
    return 1.f - 2.f / (e + 1.f);
}
// fp32 -> bf16 round-to-nearest-even (values are tame: no NaN/Inf handling needed)
__device__ __forceinline__ short f2bf(float f) {
    union { float f; unsigned u; } v; v.f = f;
    unsigned r = v.u + 0x7FFFu + ((v.u >> 16) & 1u);
    return (short)(r >> 16);
}

// ---------------- Kernel A: embW[v][c] = emb[v][:] @ Wx[:,c] + bi[c]  (both dirs via blockIdx.y) ----------------
__global__ __launch_bounds__(256) void embw_kernel(
    const float* __restrict__ emb,
    const float* __restrict__ Wx_f, const float* __restrict__ bi_f,
    const float* __restrict__ Wx_b, const float* __restrict__ bi_b,
    float* __restrict__ embW_f, float* __restrict__ embW_b)
{
    const float* Wx = blockIdx.y ? Wx_b : Wx_f;
    const float* bi = blockIdx.y ? bi_b : bi_f;
    float* embW     = blockIdx.y ? embW_b : embW_f;
    __shared__ float wx_lds[EE * 192];
    __shared__ float emb_lds[32 * EE];
    const int tid = threadIdx.x;
    const int v0 = blockIdx.x * 32;
    for (int i = tid; i < EE * 192; i += 256) wx_lds[i] = Wx[i];
    for (int i = tid; i < 32 * EE; i += 256) emb_lds[i] = emb[(size_t)v0 * EE + i];
    __syncthreads();
    const int cg = tid & 63;
    const int rg = tid >> 6;
    float acc[8][3];
    #pragma unroll
    for (int i = 0; i < 8; i++) {
        acc[i][0] = bi[cg];
        acc[i][1] = bi[cg + 64];
        acc[i][2] = bi[cg + 128];
    }
    for (int k = 0; k < EE; k++) {
        const float wx0 = wx_lds[k * 192 + cg];
        const float wx1 = wx_lds[k * 192 + cg + 64];
        const float wx2 = wx_lds[k * 192 + cg + 128];
        #pragma unroll
        for (int i = 0; i < 8; i++) {
            const float ev = emb_lds[(rg * 8 + i) * EE + k];
            acc[i][0] = fmaf(ev, wx0, acc[i][0]);
            acc[i][1] = fmaf(ev, wx1, acc[i][1]);
            acc[i][2] = fmaf(ev, wx2, acc[i][2]);
        }
    }
    #pragma unroll
    for (int i = 0; i < 8; i++) {
        const size_t row = (size_t)(v0 + rg * 8 + i) * 192;
        embW[row + cg]       = acc[i][0];
        embW[row + cg + 64]  = acc[i][1];
        embW[row + cg + 128] = acc[i][2];
    }
}

// ---------------- Kernel B v8: MFMA GRU, 16 sequences per block ----------------
// Block = 256 thr (4 waves) per (16 seqs, dir). Per step: gh = h[16x64] @ Wh[64x192] via
// mfma_f32_16x16x32_f16. Wave w owns gate cols {c, 64+c, 128+c}, c = 16w + l15:
// 3 n-tiles x 2 k-tiles = 6 MFMA/step. Weights = 6 B-frags (24 VGPR as f16) -- fits the RA.
// Fragment maps identical to attn7 (HW-verified R7): A row=l15, k=8*lhi+j; B col=l15 (tile),
// same k map; C/D col=l15, row=4*lhi+reg. h fp32 in lane regs for the blend; f16 in LDS
// (double-buffered) as next step's A operand. Barrier = lgkmcnt-only + s_barrier so the
// outb stores and depth-2 embW prefetch stay in flight across steps.
__global__ __launch_bounds__(256, 1) void gru8_kernel(
    const int* __restrict__ ids,
    const float* __restrict__ embW_f, const float* __restrict__ embW_b,
    const float* __restrict__ Wh_f, const float* __restrict__ br_f,
    const float* __restrict__ Wh_b, const float* __restrict__ br_b,
    float* __restrict__ outb,     // [B, T, 128]
    float* __restrict__ hf_out)   // [B, 64]
{
    const int tid  = threadIdx.x;
    const int w    = tid >> 6;
    const int lane = tid & 63;
    const int l15  = lane & 15;
    const int lhi  = lane >> 4;
    const int dir  = blockIdx.y;
    const int b0   = blockIdx.x * 16;
    const float* eW = dir ? embW_b : embW_f;
    const float* Wh = dir ? Wh_b : Wh_f;
    const float* br = dir ? br_b : br_f;
    const int c = 16 * w + l15;   // hidden column 0..63 owned by this lane

    // B-fragments: gate g (0=z,1=r,2=n), k-tile kt. Element jj: k = 32*kt + 8*lhi + jj,
    // col = 64*g + c.
    f16x8 bw[3][2];
    #pragma unroll
    for (int g = 0; g < 3; g++) {
        #pragma unroll
        for (int kt = 0; kt < 2; kt++) {
            #pragma unroll
            for (int jj = 0; jj < 8; jj++)
                bw[g][kt][jj] = (_Float16)Wh[(size_t)(32 * kt + 8 * lhi + jj) * 192 + 64 * g + c];
        }
    }
    const float brz = br[c], brr = br[64 + c], brn = br[128 + c];

    __shared__ __align__(16) _Float16 hlds[2][16][72];  // [buf][seq][k] (+pad)
    __shared__ int ids_s[16 * TT];
    for (int i = tid; i < 16 * TT; i += 256) ids_s[i] = ids[(size_t)b0 * TT + i];
    for (int i = tid; i < 2 * 16 * 72; i += 256) ((_Float16*)hlds)[i] = (_Float16)0.f;
    float hold[4] = {0.f, 0.f, 0.f, 0.f};   // h[4*lhi+r][c], fp32 master copy
    __syncthreads();

    const int t0 = dir ? (TT - 1) : 0;
    const int dt = dir ? -1 : 1;

    // depth-2 gx pipeline: gx[stage][gate][r], id[stage][r]
    int id0[4], id1[4];
    float gx0[3][4], gx1[3][4];
    #pragma unroll
    for (int r = 0; r < 4; r++) {
        id0[r] = ids_s[(4 * lhi + r) * TT + t0];
        id1[r] = ids_s[(4 * lhi + r) * TT + t0 + dt];
        const float* p0 = eW + (size_t)id0[r] * 192 + c;
        const float* p1 = eW + (size_t)id1[r] * 192 + c;
        #pragma unroll
        for (int g = 0; g < 3; g++) { gx0[g][r] = p0[64 * g]; gx1[g][r] = p1[64 * g]; }
    }

    int cur = 0;
    #pragma unroll 2
    for (int s = 0; s < TT; s++) {
        const int t = t0 + s * dt;
        // prefetch step s+2
        int id2[4];
        float gx2[3][4];
        if (s + 2 < TT) {
            #pragma unroll
            for (int r = 0; r < 4; r++) {
                id2[r] = ids_s[(4 * lhi + r) * TT + t + 2 * dt];
                const float* p2 = eW + (size_t)id2[r] * 192 + c;
                #pragma unroll
                for (int g = 0; g < 3; g++) gx2[g][r] = p2[64 * g];
            }
        } else {
            #pragma unroll
            for (int r = 0; r < 4; r++) {
                id2[r] = 0;
                #pragma unroll
                for (int g = 0; g < 3; g++) gx2[g][r] = 0.f;
            }
        }
        // A-fragments from LDS (f16): row l15, k = kt*32 + 8*lhi + j
        const f16x8 a0 = *(const f16x8*)&hlds[cur][l15][8 * lhi];
        const f16x8 a1 = *(const f16x8*)&hlds[cur][l15][32 + 8 * lhi];
        // 6 MFMA: gh for the 3 gates over K=64
        f32x4 az = {0.f, 0.f, 0.f, 0.f};
        f32x4 ar = {0.f, 0.f, 0.f, 0.f};
        f32x4 an = {0.f, 0.f, 0.f, 0.f};
        az = __builtin_amdgcn_mfma_f32_16x16x32_f16(a0, bw[0][0], az, 0, 0, 0);
        ar = __builtin_amdgcn_mfma_f32_16x16x32_f16(a0, bw[1][0], ar, 0, 0, 0);
        an = __builtin_amdgcn_mfma_f32_16x16x32_f16(a0, bw[2][0], an, 0, 0, 0);
        az = __builtin_amdgcn_mfma_f32_16x16x32_f16(a1, bw[0][1], az, 0, 0, 0);
        ar = __builtin_amdgcn_mfma_f32_16x16x32_f16(a1, bw[1][1], ar, 0, 0, 0);
        an = __builtin_amdgcn_mfma_f32_16x16x32_f16(a1, bw[2][1], an, 0, 0, 0);
        // gates + h update for the 4 seqs this lane covers (rows 4*lhi+r)
        #pragma unroll
        for (int r = 0; r < 4; r++) {
            const float z  = fsig(gx0[0][r] + az[r] + brz);
            const float rg = fsig(gx0[1][r] + ar[r] + brr);
            const float hh = ftanh(gx0[2][r] + rg * (an[r] + brn));
            float hnew = z * hold[r] + (1.f - z) * hh;
            hnew = (id0[r] != 0) ? hnew : hold[r];
            hold[r] = hnew;
            hlds[cur ^ 1][4 * lhi + r][c] = (_Float16)hnew;
            outb[((size_t)(b0 + 4 * lhi + r) * TT + t) * 128 + dir * 64 + c] = hnew;
        }
        cur ^= 1;
        // LDS-only drain + barrier: leaves outb stores and gx prefetch loads in flight.
        asm volatile("s_waitcnt lgkmcnt(0)\n\ts_barrier" ::: "memory");
        // shift pipeline
        #pragma unroll
        for (int r = 0; r < 4; r++) {
            id0[r] = id1[r]; id1[r] = id2[r];
            #pragma unroll
            for (int g = 0; g < 3; g++) { gx0[g][r] = gx1[g][r]; gx1[g][r] = gx2[g][r]; }
        }
    }
    if (dir == 0) {
        #pragma unroll
        for (int r = 0; r < 4; r++)
            hf_out[(size_t)(b0 + 4 * lhi + r) * 64 + c] = hold[r];
    }
}

// ---------------- Kernel C v7: MFMA keys GEMM ----------------
// One block per b, 256 thr = 4 waves. keys[t, c] = out[b,t,:128] @ Wk[:, c].
// mfma_f32_16x16x32_bf16: A row = lane&15 (=t within tile), k = 8*(lane>>4)+j;
// B col = lane&15 (=c within n-tile), same k map; C/D col=lane&15, row=4*(lane>>4)+reg (m89-verified).
// Wk staged once into LDS, pre-swizzled to B-fragment order -> one ds_read_b128 per MFMA.
#define NTILE 13   // ceil(200/16)

__global__ __launch_bounds__(256) void attn7_kernel(
    const int* __restrict__ ids,
    const float* __restrict__ outb,   // [B,T,128] fp32
    const float* __restrict__ hf,     // [B,64]
    const float* __restrict__ Wk, const float* __restrict__ bk,
    const float* __restrict__ Wq, const float* __restrict__ bq,
    const float* __restrict__ We, const float* __restrict__ be,
    float* __restrict__ ctx)          // [B,128]
{
    __shared__ __align__(16) short wk_sw[1024 * 8];  // [slot][j]; slot = ks*256 + lhi*64 + nt*16 + l15
    __shared__ float q_lds[64];
    __shared__ float we_lds[64];
    __shared__ float e_lds[TT];
    __shared__ float part[4][128];
    const int b = blockIdx.x;
    const int tid = threadIdx.x;
    const int w = tid >> 6;
    const int lane = tid & 63;
    const int l15 = lane & 15;
    const int lhi = lane >> 4;

    // Stage Wk (fp32 -> bf16) into fragment-ordered LDS. Each thread fills 4 slots of 8 values.
    #pragma unroll
    for (int i = 0; i < 4; i++) {
        const int slot = tid + 256 * i;
        const int s_l15 = slot & 15;
        const int s_nt  = (slot >> 4) & 3;
        const int s_lhi = (slot >> 6) & 3;
        const int s_ks  = slot >> 8;
        const int kbase = 32 * s_ks + 8 * s_lhi;
        const int col   = 16 * s_nt + s_l15;
        bf16x8 v;
        #pragma unroll
        for (int jj = 0; jj < 8; jj++) v[jj] = f2bf(Wk[(size_t)(kbase + jj) * 64 + col]);
        *(bf16x8*)&wk_sw[slot * 8] = v;
    }
    // q[c] = bq[c] + hf[b] @ Wq[:,c] (wave 0; coalesced column reads)
    if (tid < 64) {
        float qc = bq[tid];
        const float* hfb = hf + (size_t)b * 64;
        for (int k = 0; k < 64; k++) qc = fmaf(hfb[k], Wq[k * 64 + tid], qc);
        q_lds[tid] = qc;
        we_lds[tid] = We[tid];
    }
    __syncthreads();

    // keys + energy, 16-row tiles round-robined over the 4 waves
    for (int tile = w; tile < NTILE; tile += 4) {
        const int t0 = tile * 16;
        const int t = t0 + l15;
        f32x4 acc[4];
        #pragma unroll
        for (int nt = 0; nt < 4; nt++) { acc[nt][0] = 0.f; acc[nt][1] = 0.f; acc[nt][2] = 0.f; acc[nt][3] = 0.f; }
        #pragma unroll
        for (int ks = 0; ks < 4; ks++) {
            bf16x8 a;
            if (t < TT) {
                const float* p = outb + ((size_t)b * TT + t) * 128 + 32 * ks + 8 * lhi;
                const float4 lo = *(const float4*)p;
                const float4 hi = *(const float4*)(p + 4);
                a[0] = f2bf(lo.x); a[1] = f2bf(lo.y); a[2] = f2bf(lo.z); a[3] = f2bf(lo.w);
                a[4] = f2bf(hi.x); a[5] = f2bf(hi.y); a[6] = f2bf(hi.z); a[7] = f2bf(hi.w);
            } else {
                #pragma unroll
                for (int jj = 0; jj < 8; jj++) a[jj] = 0;
            }
            #pragma unroll
            for (int nt = 0; nt < 4; nt++) {
                const bf16x8 bf = *(const bf16x8*)&wk_sw[(ks * 256 + lhi * 64 + nt * 16 + l15) * 8];
                acc[nt] = __builtin_amdgcn_mfma_f32_16x16x32_bf16(a, bf, acc[nt], 0, 0, 0);
            }
        }
        // energy partials: ep[r] = sum_c We[c] * tanh(keys[t0+4*lhi+r][c] + q[c]); c spread over l15 x nt
        float ep0 = 0.f, ep1 = 0.f, ep2 = 0.f, ep3 = 0.f;
        #pragma unroll
        for (int nt = 0; nt < 4; nt++) {
            const int c = 16 * nt + l15;
            const float qn = q_lds[c];
            const float wen = we_lds[c];
            ep0 = fmaf(wen, ftanh(acc[nt][0] + qn), ep0);
            ep1 = fmaf(wen, ftanh(acc[nt][1] + qn), ep1);
            ep2 = fmaf(wen, ftanh(acc[nt][2] + qn), ep2);
            ep3 = fmaf(wen, ftanh(acc[nt][3] + qn), ep3);
        }
        #pragma unroll
        for (int off = 1; off < 16; off <<= 1) {
            ep0 += __shfl_xor(ep0, off);
            ep1 += __shfl_xor(ep1, off);
            ep2 += __shfl_xor(ep2, off);
            ep3 += __shfl_xor(ep3, off);
        }
        if (l15 == 0) {
            const int rbase = t0 + 4 * lhi;
            if (rbase + 0 < TT) e_lds[rbase + 0] = ep0;
            if (rbase + 1 < TT) e_lds[rbase + 1] = ep1;
            if (rbase + 2 < TT) e_lds[rbase + 2] = ep2;
            if (rbase + 3 < TT) e_lds[rbase + 3] = ep3;
        }
    }
    __syncthreads();
    // softmax over t (wave 0)
    if (w == 0) {
        const float bev = be[0];
        for (int t = lane; t < TT; t += 64) {
            float e = e_lds[t] + bev;
            if (ids[(size_t)b * TT + t] == 0) e -= 1e9f;
            e_lds[t] = e;
        }
        float m = -1e30f;
        for (int t = lane; t < TT; t += 64) m = fmaxf(m, e_lds[t]);
        #pragma unroll
        for (int off = 32; off > 0; off >>= 1) m = fmaxf(m, __shfl_xor(m, off));
        float ssum = 0.f;
        for (int t = lane; t < TT; t += 64) { const float v = __expf(e_lds[t] - m); e_lds[t] = v; ssum += v; }
        #pragma unroll
        for (int off = 32; off > 0; off >>= 1) ssum += __shfl_xor(ssum, off);
        const float inv = 1.f / ssum;
        for (int t = lane; t < TT; t += 64) e_lds[t] *= inv;
    }
    __syncthreads();
    // context (fp32): wave w covers t ≡ w (mod 4)
    float c0 = 0.f, c1 = 0.f;
    for (int t = w; t < TT; t += 4) {
        const float* orow = outb + ((size_t)b * TT + t) * 128;
        const float wt = e_lds[t];
        c0 = fmaf(wt, orow[lane], c0);
        c1 = fmaf(wt, orow[64 + lane], c1);
    }
    part[w][lane] = c0;
    part[w][64 + lane] = c1;
    __syncthreads();
    if (tid < 128)
        ctx[(size_t)b * 128 + tid] = part[0][tid] + part[1][tid] + part[2][tid] + part[3][tid];
}

// ---------------- (fallback) GRU 3-wave kernel, recompute-gx variant ----------------
template<bool USE_EMBW>
__global__ __launch_bounds__(192, 2) void gru_kernel(
    const int* __restrict__ ids,
    const float* __restrict__ embW_f, const float* __restrict__ embW_b,
    const float* __restrict__ emb,
    const float* __restrict__ Wx_f, const float* __restrict__ bi_f,
    const float* __restrict__ Wx_b, const float* __restrict__ bi_b,
    const float* __restrict__ Wh_f, const float* __restrict__ br_f,
    const float* __restrict__ Wh_b, const float* __restrict__ br_b,
    float* __restrict__ outb, float* __restrict__ hf_out)
{
    constexpr int R = 4;
    __shared__ float h_lds[R][64];
    __shared__ float rg_lds[R][64];
    __shared__ float hh_lds[R][64];
    __shared__ int ids_lds[R * TT];
    const int tid = threadIdx.x;
    const int w = tid >> 6;
    const int j = tid & 63;
    const int dir = blockIdx.y;
    const int b0 = blockIdx.x * R;
    const float* embW = dir ? embW_b : embW_f;
    const float* Wh   = dir ? Wh_b : Wh_f;
    const float* br   = dir ? br_b : br_f;
    const float* Wx   = dir ? Wx_b : Wx_f;
    const float* bi   = dir ? bi_b : bi_f;
    const int c = w * 64 + j;

    float whc[64];
    #pragma unroll
    for (int k = 0; k < 64; k++) whc[k] = Wh[k * 192 + c];
    const float brc = br[c];
    float wxc[EE];
    float bic = 0.f;
    if (!USE_EMBW) {
        #pragma unroll
        for (int k = 0; k < EE; k++) wxc[k] = Wx[k * 192 + c];
        bic = bi[c];
    }
    for (int i = tid; i < R * TT; i += 192) ids_lds[i] = ids[(size_t)b0 * TT + i];
    if (w == 0) {
        #pragma unroll
        for (int r = 0; r < R; r++) h_lds[r][j] = 0.f;
    }
    __syncthreads();

    for (int s = 0; s < TT; s++) {
        const int t = dir ? (TT - 1 - s) : s;
        int idv[R];
        float gxv[R], accv[R];
        #pragma unroll
        for (int r = 0; r < R; r++) idv[r] = ids_lds[r * TT + t];
        if (USE_EMBW) {
            #pragma unroll
            for (int r = 0; r < R; r++) gxv[r] = embW[(size_t)idv[r] * 192 + c];
        } else {
            #pragma unroll
            for (int r = 0; r < R; r++) {
                float acc = bic;
                const float* er = emb + (size_t)idv[r] * EE;
                #pragma unroll
                for (int k = 0; k < EE; k++) acc = fmaf(er[k], wxc[k], acc);
                gxv[r] = acc;
            }
        }
        #pragma unroll
        for (int r = 0; r < R; r++) {
            float acc = brc;
            const float4* h4 = (const float4*)(&h_lds[r][0]);
            #pragma unroll
            for (int k4 = 0; k4 < 16; k4++) {
                const float4 hv = h4[k4];
                acc = fmaf(hv.x, whc[4 * k4 + 0], acc);
                acc = fmaf(hv.y, whc[4 * k4 + 1], acc);
                acc = fmaf(hv.z, whc[4 * k4 + 2], acc);
                acc = fmaf(hv.w, whc[4 * k4 + 3], acc);
            }
            accv[r] = acc;
        }
        float zg[R] = {};
        if (w == 1) {
            #pragma unroll
            for (int r = 0; r < R; r++) rg_lds[r][j] = fsig(gxv[r] + accv[r]);
        } else if (w == 0) {
            #pragma unroll
            for (int r = 0; r < R; r++) zg[r] = fsig(gxv[r] + accv[r]);
        }
        __syncthreads();
        if (w == 2) {
            #pragma unroll
            for (int r = 0; r < R; r++)
                hh_lds[r][j] = ftanh(gxv[r] + rg_lds[r][j] * accv[r]);
        }
        __syncthreads();
        if (w == 0) {
            #pragma unroll
            for (int r = 0; r < R; r++) {
                const float hold = h_lds[r][j];
                float hnew = hold;
                if (idv[r] != 0) {
                    const float hh = hh_lds[r][j];
                    hnew = zg[r] * hold + (1.f - zg[r]) * hh;
                }
                h_lds[r][j] = hnew;
                outb[((size_t)(b0 + r) * TT + t) * 128 + dir * 64 + j] = hnew;
            }
        }
        __syncthreads();
    }
    if (dir == 0 && w == 0) {
        #pragma unroll
        for (int r = 0; r < R; r++) hf_out[(size_t)(b0 + r) * 64 + j] = h_lds[r][j];
    }
}

extern "C" void kernel_launch(void* const* d_in, const int* in_sizes, int n_in,
                              void* d_out, int out_size, void* d_ws, size_t ws_size,
                              hipStream_t stream) {
    const int*   ids  = (const int*)d_in[0];
    const float* emb  = (const float*)d_in[1];
    const float* Wx_f = (const float*)d_in[2];
    const float* Wh_f = (const float*)d_in[3];
    const float* bi_f = (const float*)d_in[4];
    const float* br_f = (const float*)d_in[5];
    const float* Wx_b = (const float*)d_in[6];
    const float* Wh_b = (const float*)d_in[7];
    const float* bi_b = (const float*)d_in[8];
    const float* br_b = (const float*)d_in[9];
    const float* Wk   = (const float*)d_in[10];
    const float* bk   = (const float*)d_in[11];
    const float* Wq   = (const float*)d_in[12];
    const float* bq   = (const float*)d_in[13];
    const float* We   = (const float*)d_in[14];
    const float* be   = (const float*)d_in[15];
    float* ctx = (float*)d_out;

    float* ws = (float*)d_ws;
    const size_t embw_elems = (size_t)VV * 192;
    const size_t out_elems  = (size_t)BB * TT * 128;
    const size_t hf_elems   = (size_t)BB * 64;
    const size_t need_embw  = (2 * embw_elems + out_elems + hf_elems) * sizeof(float);
    const bool use_embw = (ws_size >= need_embw);

    float *embW_f = nullptr, *embW_b = nullptr, *outb, *hf;
    if (use_embw) {
        embW_f = ws;
        embW_b = embW_f + embw_elems;
        outb   = embW_b + embw_elems;
        hf     = outb + out_elems;
    } else {
        outb = ws;
        hf   = outb + out_elems;
    }

    if (use_embw) {
        embw_kernel<<<dim3(VV / 32, 2), 256, 0, stream>>>(
            emb, Wx_f, bi_f, Wx_b, bi_b, embW_f, embW_b);
        gru8_kernel<<<dim3(BB / 16, 2), 256, 0, stream>>>(
            ids, embW_f, embW_b, Wh_f, br_f, Wh_b, br_b, outb, hf);
    } else {
        gru_kernel<false><<<dim3(BB / 4, 2), 192, 0, stream>>>(
            ids, embW_f, embW_b, emb, Wx_f, bi_f, Wx_b, bi_b,
            Wh_f, br_f, Wh_b, br_b, outb, hf);
    }
    attn7_kernel<<<BB, 256, 0, stream>>>(ids, outb, hf, Wk, bk, Wq, bq, We, be, ctx);
}